// Round 1
// baseline (692.308 us; speedup 1.0000x reference)
//
#include <hip/hip_runtime.h>
#include <cmath>

// ---------------------------------------------------------------------------
// StructuralAttentionLayer: graph transformer layer on MI355X (gfx950)
// N=50000 nodes, E=800000 edges, D=128, H=8 heads, DK=16
// Round 0: correctness-first fp32 implementation.
// ---------------------------------------------------------------------------

__device__ __forceinline__ float gelu_exact(float x) {
    return 0.5f * x * (1.0f + erff(x * 0.70710678118654752440f));
}

// ---- CSR build -------------------------------------------------------------

__global__ __launch_bounds__(256)
void hist_kernel(const int* __restrict__ dst, int* __restrict__ cnt, int E) {
    int e = blockIdx.x * 256 + threadIdx.x;
    if (e < E) atomicAdd(&cnt[dst[e]], 1);
}

// Single-block exclusive scan over n degrees. cnt[] is read as degree and
// overwritten with the exclusive prefix (becomes the scatter cursor).
__global__ __launch_bounds__(1024)
void scan_kernel(int* __restrict__ cnt, int* __restrict__ offs, int n) {
    __shared__ int wsum[16];
    const int t = threadIdx.x, wid = t >> 6, lane = t & 63;
    int running = 0;
    for (int base = 0; base < n; base += 1024) {
        int i = base + t;
        int v = (i < n) ? cnt[i] : 0;
        int incl = v;
        #pragma unroll
        for (int off = 1; off < 64; off <<= 1) {
            int u = __shfl_up(incl, off, 64);
            if (lane >= off) incl += u;
        }
        if (lane == 63) wsum[wid] = incl;
        __syncthreads();
        int wprefix = 0, tot = 0;
        #pragma unroll
        for (int w = 0; w < 16; ++w) {
            int s = wsum[w];
            if (w < wid) wprefix += s;
            tot += s;
        }
        int excl = running + wprefix + (incl - v);
        if (i < n) { offs[i] = excl; cnt[i] = excl; }
        running += tot;
        __syncthreads();
    }
    if (t == 0) offs[n] = running;
}

__global__ __launch_bounds__(256)
void scatter_kernel(const int* __restrict__ src, const int* __restrict__ dst,
                    int* __restrict__ cursor, int* __restrict__ esrc, int E) {
    int e = blockIdx.x * 256 + threadIdx.x;
    if (e < E) {
        int p = atomicAdd(&cursor[dst[e]], 1);
        esrc[p] = src[e];
    }
}

// ---- GEMM: C[r][c] = act(sum_d A[r][d]*W[d][c] + bias[c]) (+ resid) --------
// Block tile 64 rows x 64 cols, thread tile 4x4, K-chunks of 128.

__global__ __launch_bounds__(256)
void gemm_kernel(const float* __restrict__ A, const float* __restrict__ W,
                 const float* __restrict__ bias, float* __restrict__ C,
                 const float* __restrict__ resid,
                 int n_rows, int K, int ncols, int act) {
    __shared__ float As[64][128];
    __shared__ float Ws[128][64];
    const int t  = threadIdx.x;
    const int rb = blockIdx.x * 64;
    const int cb = blockIdx.y * 64;
    const int r0 = (t >> 4) << 2;   // 0..60
    const int c0 = (t & 15) << 2;   // 0..60
    float acc[4][4] = {};

    for (int kc = 0; kc < K; kc += 128) {
        // stage A tile (64 x 128)
        for (int i = t; i < 64 * 32; i += 256) {
            int r = i >> 5, j4 = (i & 31) << 2;
            float4 val = make_float4(0.f, 0.f, 0.f, 0.f);
            if (rb + r < n_rows)
                val = *(const float4*)&A[(size_t)(rb + r) * K + kc + j4];
            *(float4*)&As[r][j4] = val;
        }
        // stage W tile (128 x 64)
        for (int i = t; i < 128 * 16; i += 256) {
            int d = i >> 4, j4 = (i & 15) << 2;
            *(float4*)&Ws[d][j4] = *(const float4*)&W[(size_t)(kc + d) * ncols + cb + j4];
        }
        __syncthreads();

        #pragma unroll 4
        for (int d = 0; d < 128; ++d) {
            float4 w = *(const float4*)&Ws[d][c0];
            float a0 = As[r0 + 0][d];
            float a1 = As[r0 + 1][d];
            float a2 = As[r0 + 2][d];
            float a3 = As[r0 + 3][d];
            acc[0][0] = fmaf(a0, w.x, acc[0][0]);
            acc[0][1] = fmaf(a0, w.y, acc[0][1]);
            acc[0][2] = fmaf(a0, w.z, acc[0][2]);
            acc[0][3] = fmaf(a0, w.w, acc[0][3]);
            acc[1][0] = fmaf(a1, w.x, acc[1][0]);
            acc[1][1] = fmaf(a1, w.y, acc[1][1]);
            acc[1][2] = fmaf(a1, w.z, acc[1][2]);
            acc[1][3] = fmaf(a1, w.w, acc[1][3]);
            acc[2][0] = fmaf(a2, w.x, acc[2][0]);
            acc[2][1] = fmaf(a2, w.y, acc[2][1]);
            acc[2][2] = fmaf(a2, w.z, acc[2][2]);
            acc[2][3] = fmaf(a2, w.w, acc[2][3]);
            acc[3][0] = fmaf(a3, w.x, acc[3][0]);
            acc[3][1] = fmaf(a3, w.y, acc[3][1]);
            acc[3][2] = fmaf(a3, w.z, acc[3][2]);
            acc[3][3] = fmaf(a3, w.w, acc[3][3]);
        }
        __syncthreads();
    }

    #pragma unroll
    for (int i2 = 0; i2 < 4; ++i2) {
        int r = rb + r0 + i2;
        if (r >= n_rows) break;
        #pragma unroll
        for (int j = 0; j < 4; ++j) {
            int c = cb + c0 + j;
            float vv = acc[i2][j] + bias[c];
            if (act == 1) vv = gelu_exact(vv);
            if (resid) vv += resid[(size_t)r * ncols + c];
            C[(size_t)r * ncols + c] = vv;
        }
    }
}

// ---- Attention aggregation: one wave per dst node, online softmax ----------
// lane l holds dims {2l, 2l+1}; head = l >> 3 (8 lanes per head, 16 dims).

__global__ __launch_bounds__(256)
void attn_kernel(const float* __restrict__ q, const float* __restrict__ k,
                 const float* __restrict__ v, const float* __restrict__ x,
                 const int* __restrict__ offs, const int* __restrict__ esrc,
                 float* __restrict__ h, int n) {
    const int wave = threadIdx.x >> 6;
    const int lane = threadIdx.x & 63;
    const int node = blockIdx.x * 4 + wave;
    if (node >= n) return;

    const float2 qv = *(const float2*)&q[(size_t)node * 128 + lane * 2];
    const int e0 = offs[node], e1 = offs[node + 1];

    float m = -INFINITY, l = 0.f;
    float2 acc = make_float2(0.f, 0.f);

    for (int j = e0; j < e1; ++j) {
        int s = esrc[j];
        float2 kv = *(const float2*)&k[(size_t)s * 128 + lane * 2];
        float p = qv.x * kv.x + qv.y * kv.y;
        p += __shfl_xor(p, 1, 64);
        p += __shfl_xor(p, 2, 64);
        p += __shfl_xor(p, 4, 64);
        float score = p * 0.25f;                 // / sqrt(16)
        float mn = fmaxf(m, score);
        float scale = __expf(m - mn);            // first iter: exp(-inf)=0
        float pe = __expf(score - mn);
        l = l * scale + pe;
        float2 vv = *(const float2*)&v[(size_t)s * 128 + lane * 2];
        acc.x = acc.x * scale + pe * vv.x;
        acc.y = acc.y * scale + pe * vv.y;
        m = mn;
    }

    float inv = 1.f / (l + 1e-16f);              // matches ex/(den+1e-16)
    float2 xv = *(const float2*)&x[(size_t)node * 128 + lane * 2];
    float2 hv = make_float2(acc.x * inv + xv.x, acc.y * inv + xv.y);
    *(float2*)&h[(size_t)node * 128 + lane * 2] = hv;
}

// ---- LayerNorm: one wave per row -------------------------------------------

__global__ __launch_bounds__(256)
void ln_kernel(const float* __restrict__ h, const float* __restrict__ g,
               const float* __restrict__ b, float* __restrict__ hn, int n) {
    const int wave = threadIdx.x >> 6;
    const int lane = threadIdx.x & 63;
    const int node = blockIdx.x * 4 + wave;
    if (node >= n) return;

    float2 hv = *(const float2*)&h[(size_t)node * 128 + lane * 2];
    float s  = hv.x + hv.y;
    float s2 = hv.x * hv.x + hv.y * hv.y;
    #pragma unroll
    for (int off = 1; off < 64; off <<= 1) {
        s  += __shfl_xor(s, off, 64);
        s2 += __shfl_xor(s2, off, 64);
    }
    float mu  = s * (1.f / 128.f);
    float var = s2 * (1.f / 128.f) - mu * mu;
    float rstd = rsqrtf(var + 1e-5f);
    float2 gv = *(const float2*)&g[lane * 2];
    float2 bv = *(const float2*)&b[lane * 2];
    float2 o = make_float2((hv.x - mu) * rstd * gv.x + bv.x,
                           (hv.y - mu) * rstd * gv.y + bv.y);
    *(float2*)&hn[(size_t)node * 128 + lane * 2] = o;
}

// ---------------------------------------------------------------------------

extern "C" void kernel_launch(void* const* d_in, const int* in_sizes, int n_in,
                              void* d_out, int out_size, void* d_ws, size_t ws_size,
                              hipStream_t stream) {
    const float* x    = (const float*)d_in[0];
    const int*   ei   = (const int*)d_in[1];
    const float* Wq   = (const float*)d_in[2];
    const float* bq   = (const float*)d_in[3];
    const float* Wk   = (const float*)d_in[4];
    const float* bk   = (const float*)d_in[5];
    const float* Wv   = (const float*)d_in[6];
    const float* bv   = (const float*)d_in[7];
    const float* ln_g = (const float*)d_in[8];
    const float* ln_b = (const float*)d_in[9];
    const float* W1   = (const float*)d_in[10];
    const float* b1   = (const float*)d_in[11];
    const float* W2   = (const float*)d_in[12];
    const float* b2   = (const float*)d_in[13];
    float* out = (float*)d_out;

    const int D = 128;
    const int N = in_sizes[0] / D;
    const int E = in_sizes[1] / 2;
    const int* src = ei;
    const int* dst = ei + E;

    const size_t ND = (size_t)N * D;
    float* qb = (float*)d_ws;
    float* kb = qb + ND;
    float* vb = kb + ND;
    float* hb = vb + ND;
    int* cnt  = (int*)(hb + ND);
    int* offs = cnt + N;
    int* esrc = offs + N + 1;
    float* hnb = qb;   // alias: Q dead after attention
    float* hid = kb;   // alias: [N,256] over K,V (dead after attention)

    // CSR build (by dst)
    hipMemsetAsync(cnt, 0, sizeof(int) * N, stream);
    hist_kernel<<<(E + 255) / 256, 256, 0, stream>>>(dst, cnt, E);
    scan_kernel<<<1, 1024, 0, stream>>>(cnt, offs, N);
    scatter_kernel<<<(E + 255) / 256, 256, 0, stream>>>(src, dst, cnt, esrc, E);

    // Q/K/V projections
    const int rtiles = (N + 63) / 64;
    dim3 blk(256);
    dim3 g128(rtiles, 2);
    gemm_kernel<<<g128, blk, 0, stream>>>(x, Wq, bq, qb, nullptr, N, 128, 128, 0);
    gemm_kernel<<<g128, blk, 0, stream>>>(x, Wk, bk, kb, nullptr, N, 128, 128, 0);
    gemm_kernel<<<g128, blk, 0, stream>>>(x, Wv, bv, vb, nullptr, N, 128, 128, 0);

    // attention + residual -> h
    const int nwb = (N + 3) / 4;
    attn_kernel<<<nwb, 256, 0, stream>>>(qb, kb, vb, x, offs, esrc, hb, N);

    // LN -> hn
    ln_kernel<<<nwb, 256, 0, stream>>>(hb, ln_g, ln_b, hnb, N);

    // FFN
    dim3 g256(rtiles, 4);
    gemm_kernel<<<g256, blk, 0, stream>>>(hnb, W1, b1, hid, nullptr, N, 128, 256, 1);
    gemm_kernel<<<g128, blk, 0, stream>>>(hid, W2, b2, out, hb, N, 256, 128, 0);
}

// Round 2
// 444.338 us; speedup vs baseline: 1.5581x; 1.5581x over previous
//
#include <hip/hip_runtime.h>
#include <cmath>

// ---------------------------------------------------------------------------
// StructuralAttentionLayer on MI355X (gfx950)
// N=50000, E=800000, D=128, H=8, DK=16
// Round 1: bf16 MFMA GEMMs + bf16 K/V gather in attention.
// ---------------------------------------------------------------------------

typedef short v8s __attribute__((ext_vector_type(8)));   // 8 bf16 (4 VGPRs)
typedef float v4f __attribute__((ext_vector_type(4)));   // 4 fp32 acc

__device__ __forceinline__ float gelu_exact(float x) {
    return 0.5f * x * (1.0f + erff(x * 0.70710678118654752440f));
}

__device__ __forceinline__ unsigned short f2bf(float f) {
    unsigned int u = __float_as_uint(f);
    u = (u + 0x7fffu + ((u >> 16) & 1u)) >> 16;
    return (unsigned short)u;
}

__device__ __forceinline__ float2 bf2_to_f2(unsigned int u) {
    float2 r;
    r.x = __uint_as_float(u << 16);
    r.y = __uint_as_float(u & 0xffff0000u);
    return r;
}

// ---- CSR build -------------------------------------------------------------

__global__ __launch_bounds__(256)
void hist_kernel(const int* __restrict__ dst, int* __restrict__ cnt, int E) {
    int e = blockIdx.x * 256 + threadIdx.x;
    if (e < E) atomicAdd(&cnt[dst[e]], 1);
}

__global__ __launch_bounds__(1024)
void scan_kernel(int* __restrict__ cnt, int* __restrict__ offs, int n) {
    __shared__ int wsum[16];
    const int t = threadIdx.x, wid = t >> 6, lane = t & 63;
    int running = 0;
    for (int base = 0; base < n; base += 1024) {
        int i = base + t;
        int v = (i < n) ? cnt[i] : 0;
        int incl = v;
        #pragma unroll
        for (int off = 1; off < 64; off <<= 1) {
            int u = __shfl_up(incl, off, 64);
            if (lane >= off) incl += u;
        }
        if (lane == 63) wsum[wid] = incl;
        __syncthreads();
        int wprefix = 0, tot = 0;
        #pragma unroll
        for (int w = 0; w < 16; ++w) {
            int s = wsum[w];
            if (w < wid) wprefix += s;
            tot += s;
        }
        int excl = running + wprefix + (incl - v);
        if (i < n) { offs[i] = excl; cnt[i] = excl; }
        running += tot;
        __syncthreads();
    }
    if (t == 0) offs[n] = running;
}

__global__ __launch_bounds__(256)
void scatter_kernel(const int* __restrict__ src, const int* __restrict__ dst,
                    int* __restrict__ cursor, int* __restrict__ esrc, int E) {
    int e = blockIdx.x * 256 + threadIdx.x;
    if (e < E) {
        int p = atomicAdd(&cursor[dst[e]], 1);
        esrc[p] = src[e];
    }
}

// ---- casts -----------------------------------------------------------------

__global__ __launch_bounds__(256)
void cast_bf16_kernel(const float* __restrict__ in, unsigned short* __restrict__ out, int n4) {
    int i = blockIdx.x * 256 + threadIdx.x;
    if (i < n4) {
        float4 v = *(const float4*)&in[i * 4];
        ushort4 o;
        o.x = f2bf(v.x); o.y = f2bf(v.y); o.z = f2bf(v.z); o.w = f2bf(v.w);
        *(ushort4*)&out[i * 4] = o;
    }
}

// Wt[c][k] = bf16(W[k][c]);  Wt is [ncols x K]
__global__ __launch_bounds__(256)
void transpose_cast_kernel(const float* __restrict__ W, unsigned short* __restrict__ Wt,
                           int K, int ncols) {
    int i = blockIdx.x * 256 + threadIdx.x;
    if (i < K * ncols) {
        int c = i / K, k = i % K;
        Wt[i] = f2bf(W[(size_t)k * ncols + c]);
    }
}

// ---- bf16 MFMA GEMM --------------------------------------------------------
// C[r][c] = act(sum_k A[r][k] * B[k][c] + bias[c]) (+resid)
// A: [n_rows x K] bf16, Bt: [ncols x K] bf16 (transposed weights).
// Block: 256 threads = 4 waves (2x2), tile 128x128, K-chunks of 128.
// LDS holds fragments in MFMA order: frag[tile][chunk][lane] of 8 bf16,
// so fragment reads are ds_read_b128 at lane*16 (conflict-free).

__global__ __launch_bounds__(256)
void mfma_gemm_kernel(const unsigned short* __restrict__ A,
                      const unsigned short* __restrict__ Bt,
                      const float* __restrict__ bias,
                      unsigned short* __restrict__ Cb,   // bf16 out (or null)
                      float* __restrict__ Cf,            // fp32 out (or null)
                      const float* __restrict__ resid,   // fp32 resid (or null)
                      int n_rows, int K, int ncols, int act) {
    __shared__ v8s As[2048];   // 8 mtiles x 4 chunks x 64 lanes
    __shared__ v8s Bs[2048];

    const int t = threadIdx.x;
    const int l = t & 63;
    const int w = t >> 6;
    const int mhalf = w & 1, nhalf = w >> 1;
    const int rb = blockIdx.x * 128;
    const int cb = blockIdx.y * 128;

    v4f acc[4][4];
    #pragma unroll
    for (int i = 0; i < 4; ++i)
        #pragma unroll
        for (int j = 0; j < 4; ++j)
            acc[i][j] = (v4f){0.f, 0.f, 0.f, 0.f};

    const int r = t & 127;           // staging row within tile
    const int tile = r >> 4, m = r & 15;

    for (int kc = 0; kc < K; kc += 128) {
        #pragma unroll
        for (int it = 0; it < 8; ++it) {
            int k8 = (t >> 7) * 8 + it * 16;
            int chunk = k8 >> 5, j = (k8 >> 3) & 3;
            int dstidx = (tile * 4 + chunk) * 64 + j * 16 + m;
            v8s av = {0, 0, 0, 0, 0, 0, 0, 0};
            if (rb + r < n_rows)
                av = *(const v8s*)&A[(size_t)(rb + r) * K + kc + k8];
            As[dstidx] = av;
            Bs[dstidx] = *(const v8s*)&Bt[(size_t)(cb + r) * K + kc + k8];
        }
        __syncthreads();

        #pragma unroll
        for (int c = 0; c < 4; ++c) {
            v8s a[4], b[4];
            #pragma unroll
            for (int i = 0; i < 4; ++i)
                a[i] = As[((mhalf * 4 + i) * 4 + c) * 64 + l];
            #pragma unroll
            for (int j = 0; j < 4; ++j)
                b[j] = Bs[((nhalf * 4 + j) * 4 + c) * 64 + l];
            #pragma unroll
            for (int i = 0; i < 4; ++i)
                #pragma unroll
                for (int j = 0; j < 4; ++j)
                    acc[i][j] = __builtin_amdgcn_mfma_f32_16x16x32_bf16(a[i], b[j], acc[i][j], 0, 0, 0);
        }
        __syncthreads();
    }

    // Epilogue. C/D layout: col = lane&15, row = (lane>>4)*4 + reg.
    const int coll = l & 15;
    const int rowl = (l >> 4) * 2;   // *4 regs but acc reg gives +reg; base quad row:
    #pragma unroll
    for (int i = 0; i < 4; ++i) {
        int rtile = rb + (mhalf * 4 + i) * 16 + (l >> 4) * 4;
        #pragma unroll
        for (int j = 0; j < 4; ++j) {
            int c = cb + (nhalf * 4 + j) * 16 + coll;
            float bi = bias[c];
            #pragma unroll
            for (int reg = 0; reg < 4; ++reg) {
                int rr = rtile + reg;
                if (rr >= n_rows) continue;
                float vv = acc[i][j][reg] + bi;
                if (act) vv = gelu_exact(vv);
                if (Cf) {
                    float o = vv;
                    if (resid) o += resid[(size_t)rr * ncols + c];
                    Cf[(size_t)rr * ncols + c] = o;
                } else {
                    Cb[(size_t)rr * ncols + c] = f2bf(vv);
                }
            }
        }
    }
    (void)rowl;
}

// ---- Attention aggregation (bf16 q/k/v) ------------------------------------
// One wave per dst node; lane l holds dims {2l,2l+1}; head = l>>3.

__global__ __launch_bounds__(256)
void attn_kernel(const unsigned short* __restrict__ q, const unsigned short* __restrict__ k,
                 const unsigned short* __restrict__ v, const float* __restrict__ x,
                 const int* __restrict__ offs, const int* __restrict__ esrc,
                 float* __restrict__ h, int n) {
    const int wave = threadIdx.x >> 6;
    const int lane = threadIdx.x & 63;
    const int node = blockIdx.x * 4 + wave;
    if (node >= n) return;

    const float2 qv = bf2_to_f2(*(const unsigned int*)&q[(size_t)node * 128 + lane * 2]);
    const int e0 = offs[node], e1 = offs[node + 1];

    float m = -INFINITY, l = 0.f;
    float2 acc = make_float2(0.f, 0.f);

    int j = e0;
    for (; j + 2 <= e1; j += 2) {
        int s0 = esrc[j], s1 = esrc[j + 1];
        unsigned int ku0 = *(const unsigned int*)&k[(size_t)s0 * 128 + lane * 2];
        unsigned int ku1 = *(const unsigned int*)&k[(size_t)s1 * 128 + lane * 2];
        unsigned int vu0 = *(const unsigned int*)&v[(size_t)s0 * 128 + lane * 2];
        unsigned int vu1 = *(const unsigned int*)&v[(size_t)s1 * 128 + lane * 2];
        float2 k0 = bf2_to_f2(ku0), k1 = bf2_to_f2(ku1);
        float p0 = qv.x * k0.x + qv.y * k0.y;
        float p1 = qv.x * k1.x + qv.y * k1.y;
        p0 += __shfl_xor(p0, 1, 64); p1 += __shfl_xor(p1, 1, 64);
        p0 += __shfl_xor(p0, 2, 64); p1 += __shfl_xor(p1, 2, 64);
        p0 += __shfl_xor(p0, 4, 64); p1 += __shfl_xor(p1, 4, 64);
        float sc0 = p0 * 0.25f, sc1 = p1 * 0.25f;
        float mn = fmaxf(m, fmaxf(sc0, sc1));
        float scale = __expf(m - mn);
        float pe0 = __expf(sc0 - mn);
        float pe1 = __expf(sc1 - mn);
        l = l * scale + pe0 + pe1;
        float2 v0 = bf2_to_f2(vu0), v1 = bf2_to_f2(vu1);
        acc.x = acc.x * scale + pe0 * v0.x + pe1 * v1.x;
        acc.y = acc.y * scale + pe0 * v0.y + pe1 * v1.y;
        m = mn;
    }
    if (j < e1) {
        int s0 = esrc[j];
        float2 k0 = bf2_to_f2(*(const unsigned int*)&k[(size_t)s0 * 128 + lane * 2]);
        float p0 = qv.x * k0.x + qv.y * k0.y;
        p0 += __shfl_xor(p0, 1, 64);
        p0 += __shfl_xor(p0, 2, 64);
        p0 += __shfl_xor(p0, 4, 64);
        float sc0 = p0 * 0.25f;
        float mn = fmaxf(m, sc0);
        float scale = __expf(m - mn);
        float pe0 = __expf(sc0 - mn);
        l = l * scale + pe0;
        float2 v0 = bf2_to_f2(*(const unsigned int*)&v[(size_t)s0 * 128 + lane * 2]);
        acc.x = acc.x * scale + pe0 * v0.x;
        acc.y = acc.y * scale + pe0 * v0.y;
        m = mn;
    }

    float inv = 1.f / (l + 1e-16f);
    float2 xv = *(const float2*)&x[(size_t)node * 128 + lane * 2];
    float2 hv = make_float2(acc.x * inv + xv.x, acc.y * inv + xv.y);
    *(float2*)&h[(size_t)node * 128 + lane * 2] = hv;
}

// ---- LayerNorm (fp32 in, bf16 out) -----------------------------------------

__global__ __launch_bounds__(256)
void ln_kernel(const float* __restrict__ h, const float* __restrict__ g,
               const float* __restrict__ b, unsigned short* __restrict__ hn, int n) {
    const int wave = threadIdx.x >> 6;
    const int lane = threadIdx.x & 63;
    const int node = blockIdx.x * 4 + wave;
    if (node >= n) return;

    float2 hv = *(const float2*)&h[(size_t)node * 128 + lane * 2];
    float s  = hv.x + hv.y;
    float s2 = hv.x * hv.x + hv.y * hv.y;
    #pragma unroll
    for (int off = 1; off < 64; off <<= 1) {
        s  += __shfl_xor(s, off, 64);
        s2 += __shfl_xor(s2, off, 64);
    }
    float mu  = s * (1.f / 128.f);
    float var = s2 * (1.f / 128.f) - mu * mu;
    float rstd = rsqrtf(var + 1e-5f);
    float2 gv = *(const float2*)&g[lane * 2];
    float2 bv = *(const float2*)&b[lane * 2];
    ushort2 o;
    o.x = f2bf((hv.x - mu) * rstd * gv.x + bv.x);
    o.y = f2bf((hv.y - mu) * rstd * gv.y + bv.y);
    *(ushort2*)&hn[(size_t)node * 128 + lane * 2] = o;
}

// ---------------------------------------------------------------------------

extern "C" void kernel_launch(void* const* d_in, const int* in_sizes, int n_in,
                              void* d_out, int out_size, void* d_ws, size_t ws_size,
                              hipStream_t stream) {
    const float* x    = (const float*)d_in[0];
    const int*   ei   = (const int*)d_in[1];
    const float* Wq   = (const float*)d_in[2];
    const float* bq   = (const float*)d_in[3];
    const float* Wk   = (const float*)d_in[4];
    const float* bk   = (const float*)d_in[5];
    const float* Wv   = (const float*)d_in[6];
    const float* bv   = (const float*)d_in[7];
    const float* ln_g = (const float*)d_in[8];
    const float* ln_b = (const float*)d_in[9];
    const float* W1   = (const float*)d_in[10];
    const float* b1   = (const float*)d_in[11];
    const float* W2   = (const float*)d_in[12];
    const float* b2   = (const float*)d_in[13];
    float* out = (float*)d_out;

    const int D = 128;
    const int N = in_sizes[0] / D;
    const int E = in_sizes[1] / 2;
    const int* src = ei;
    const int* dst = ei + E;

    const size_t ND = (size_t)N * D;
    unsigned short* xb = (unsigned short*)d_ws;            // N*128 bf16
    unsigned short* qb = xb + ND;
    unsigned short* kb = qb + ND;
    unsigned short* vb = kb + ND;
    float* hb = (float*)(vb + ND);                         // N*128 fp32
    unsigned short* wqt = (unsigned short*)(hb + ND);
    unsigned short* wkt = wqt + 128 * 128;
    unsigned short* wvt = wkt + 128 * 128;
    unsigned short* w1t = wvt + 128 * 128;                 // 256*128
    unsigned short* w2t = w1t + 256 * 128;                 // 128*256
    int* cnt  = (int*)(w2t + 128 * 256);
    int* offs = cnt + N;
    int* esrc = offs + N + 1;
    unsigned short* hnb = vb;   // alias: v dead after attention
    unsigned short* hid = qb;   // alias: q,k dead after attention (N*256 bf16)

    // CSR build (by dst)
    hipMemsetAsync(cnt, 0, sizeof(int) * N, stream);
    hist_kernel<<<(E + 255) / 256, 256, 0, stream>>>(dst, cnt, E);
    scan_kernel<<<1, 1024, 0, stream>>>(cnt, offs, N);
    scatter_kernel<<<(E + 255) / 256, 256, 0, stream>>>(src, dst, cnt, esrc, E);

    // casts
    cast_bf16_kernel<<<(int)((ND / 4 + 255) / 256), 256, 0, stream>>>(x, xb, (int)(ND / 4));
    transpose_cast_kernel<<<(128 * 128 + 255) / 256, 256, 0, stream>>>(Wq, wqt, 128, 128);
    transpose_cast_kernel<<<(128 * 128 + 255) / 256, 256, 0, stream>>>(Wk, wkt, 128, 128);
    transpose_cast_kernel<<<(128 * 128 + 255) / 256, 256, 0, stream>>>(Wv, wvt, 128, 128);
    transpose_cast_kernel<<<(128 * 256 + 255) / 256, 256, 0, stream>>>(W1, w1t, 128, 256);
    transpose_cast_kernel<<<(256 * 128 + 255) / 256, 256, 0, stream>>>(W2, w2t, 256, 128);

    // Q/K/V projections (bf16 out)
    const int rt = (N + 127) / 128;
    dim3 blk(256);
    mfma_gemm_kernel<<<dim3(rt, 1), blk, 0, stream>>>(xb, wqt, bq, qb, nullptr, nullptr, N, 128, 128, 0);
    mfma_gemm_kernel<<<dim3(rt, 1), blk, 0, stream>>>(xb, wkt, bk, kb, nullptr, nullptr, N, 128, 128, 0);
    mfma_gemm_kernel<<<dim3(rt, 1), blk, 0, stream>>>(xb, wvt, bv, vb, nullptr, nullptr, N, 128, 128, 0);

    // attention + residual -> h (fp32)
    const int nwb = (N + 3) / 4;
    attn_kernel<<<nwb, 256, 0, stream>>>(qb, kb, vb, x, offs, esrc, hb, N);

    // LN -> hn (bf16)
    ln_kernel<<<nwb, 256, 0, stream>>>(hb, ln_g, ln_b, hnb, N);

    // FFN
    mfma_gemm_kernel<<<dim3(rt, 2), blk, 0, stream>>>(hnb, w1t, b1, hid, nullptr, nullptr, N, 128, 256, 1);
    mfma_gemm_kernel<<<dim3(rt, 1), blk, 0, stream>>>(hid, w2t, b2, nullptr, out, hb, N, 256, 128, 0);
}

// Round 3
// 366.509 us; speedup vs baseline: 1.8889x; 1.2124x over previous
//
#include <hip/hip_runtime.h>
#include <cmath>

// ---------------------------------------------------------------------------
// StructuralAttentionLayer on MI355X (gfx950)
// N=50000, E=800000, D=128, H=8, DK=16
// Round 2: parallel scan, fused QKV GEMM (fp32-A staging, packed KV out),
//          attention unroll-4 with fused LayerNorm, single prep kernel.
// ---------------------------------------------------------------------------

typedef short v8s __attribute__((ext_vector_type(8)));   // 8 bf16 (4 VGPRs)
typedef float v4f __attribute__((ext_vector_type(4)));   // 4 fp32 acc

__device__ __forceinline__ float gelu_exact(float x) {
    return 0.5f * x * (1.0f + erff(x * 0.70710678118654752440f));
}

__device__ __forceinline__ unsigned short f2bf(float f) {
    unsigned int u = __float_as_uint(f);
    u = (u + 0x7fffu + ((u >> 16) & 1u)) >> 16;
    return (unsigned short)u;
}

__device__ __forceinline__ float2 bf2_to_f2(unsigned int u) {
    float2 r;
    r.x = __uint_as_float(u << 16);
    r.y = __uint_as_float(u & 0xffff0000u);
    return r;
}

// ---- CSR build -------------------------------------------------------------

__global__ __launch_bounds__(256)
void hist_kernel(const int* __restrict__ dst, int* __restrict__ cnt, int E) {
    int e = blockIdx.x * 256 + threadIdx.x;
    if (e < E) atomicAdd(&cnt[dst[e]], 1);
}

// Block-local exclusive scan; per-block total to bsum.
__global__ __launch_bounds__(256)
void scan_blk_kernel(const int* __restrict__ cnt, int* __restrict__ offs,
                     int* __restrict__ bsum, int n) {
    __shared__ int ws[4];
    const int t = threadIdx.x, wid = t >> 6, lane = t & 63;
    int i = blockIdx.x * 256 + t;
    int v = (i < n) ? cnt[i] : 0;
    int incl = v;
    #pragma unroll
    for (int off = 1; off < 64; off <<= 1) {
        int u = __shfl_up(incl, off, 64);
        if (lane >= off) incl += u;
    }
    if (lane == 63) ws[wid] = incl;
    __syncthreads();
    int prefix = 0, tot = 0;
    #pragma unroll
    for (int w = 0; w < 4; ++w) {
        int s = ws[w];
        if (w < wid) prefix += s;
        tot += s;
    }
    if (i < n) offs[i] = prefix + incl - v;
    if (t == 0) bsum[blockIdx.x] = tot;
}

// Exclusive scan of block sums (nb <= 256), single block.
__global__ __launch_bounds__(256)
void scan_top_kernel(int* __restrict__ bsum, int nb) {
    __shared__ int ws[4];
    const int t = threadIdx.x, wid = t >> 6, lane = t & 63;
    int v = (t < nb) ? bsum[t] : 0;
    int incl = v;
    #pragma unroll
    for (int off = 1; off < 64; off <<= 1) {
        int u = __shfl_up(incl, off, 64);
        if (lane >= off) incl += u;
    }
    if (lane == 63) ws[wid] = incl;
    __syncthreads();
    int prefix = 0;
    #pragma unroll
    for (int w = 0; w < 4; ++w)
        if (w < wid) prefix += ws[w];
    if (t < nb) bsum[t] = prefix + incl - v;
}

__global__ __launch_bounds__(256)
void scan_add_kernel(int* __restrict__ offs, const int* __restrict__ bsum,
                     int* __restrict__ cursor, int n, int E) {
    int i = blockIdx.x * 256 + threadIdx.x;
    if (i < n) {
        int o = offs[i] + bsum[blockIdx.x];
        offs[i] = o;
        cursor[i] = o;
    }
    if (i == n) offs[n] = E;
}

__global__ __launch_bounds__(256)
void scatter_kernel(const int* __restrict__ src, const int* __restrict__ dst,
                    int* __restrict__ cursor, int* __restrict__ esrc, int E) {
    int e = blockIdx.x * 256 + threadIdx.x;
    if (e < E) {
        int p = atomicAdd(&cursor[dst[e]], 1);
        esrc[p] = src[e];
    }
}

// ---- prep: all weight transposes (fp32 -> bf16, [col][k]) + bias concat ----
// wcat: 3 x [128x128] (Wq,Wk,Wv), w1t: [256x128], w2t: [128x256]
// bcat: [bq(128) bk(128) bv(128) b1(256) b2(128)]

__global__ __launch_bounds__(256)
void prep_kernel(const float* __restrict__ Wq, const float* __restrict__ Wk,
                 const float* __restrict__ Wv, const float* __restrict__ W1,
                 const float* __restrict__ W2,
                 const float* __restrict__ bq, const float* __restrict__ bk,
                 const float* __restrict__ bv, const float* __restrict__ b1,
                 const float* __restrict__ b2,
                 unsigned short* __restrict__ wcat, unsigned short* __restrict__ w1t,
                 unsigned short* __restrict__ w2t, float* __restrict__ bcat) {
    int i = blockIdx.x * 256 + threadIdx.x;
    if (i < 49152) {                       // 3 x 128x128
        int m = i >> 14, j = i & 16383;
        int c = j >> 7, k = j & 127;
        const float* W = (m == 0) ? Wq : (m == 1) ? Wk : Wv;
        wcat[i] = f2bf(W[k * 128 + c]);
    } else if (i < 49152 + 32768) {        // W1: [256 cols x 128 k]
        int j = i - 49152;
        int c = j >> 7, k = j & 127;
        w1t[j] = f2bf(W1[k * 256 + c]);
    } else if (i < 49152 + 65536) {        // W2: [128 cols x 256 k]
        int j = i - 49152 - 32768;
        int c = j >> 8, k = j & 255;
        w2t[j] = f2bf(W2[k * 128 + c]);
    } else if (i < 49152 + 65536 + 768) {
        int j = i - 49152 - 65536;
        float v;
        if (j < 128)      v = bq[j];
        else if (j < 256) v = bk[j - 128];
        else if (j < 384) v = bv[j - 256];
        else if (j < 640) v = b1[j - 384];
        else              v = b2[j - 640];
        bcat[j] = v;
    }
}

// ---- fused QKV GEMM --------------------------------------------------------
// A = x fp32 [N x 128]; blockIdx.y in {0,1,2} selects Wq/Wk/Wv.
// y=0 -> qb bf16 linear; y=1 -> kvb k-slots; y=2 -> kvb v-slots.
// kvb (as ushort): row n, dim d: k at n*256 + (d>>1)*4 + (d&1), v at +2.

__global__ __launch_bounds__(256)
void qkv_gemm_kernel(const float* __restrict__ A,
                     const unsigned short* __restrict__ wcat,
                     const float* __restrict__ bcat,
                     unsigned short* __restrict__ qb,
                     unsigned short* __restrict__ kvb,
                     int n_rows) {
    __shared__ v8s As[2048];
    __shared__ v8s Bs[2048];

    const int t = threadIdx.x;
    const int l = t & 63;
    const int w = t >> 6;
    const int mhalf = w & 1, nhalf = w >> 1;
    const int rb = blockIdx.x * 128;
    const int y  = blockIdx.y;
    const unsigned short* Bt = wcat + y * 16384;
    const float* bias = bcat + y * 128;

    v4f acc[4][4];
    #pragma unroll
    for (int i = 0; i < 4; ++i)
        #pragma unroll
        for (int j = 0; j < 4; ++j)
            acc[i][j] = (v4f){0.f, 0.f, 0.f, 0.f};

    const int r = t & 127;
    const int tile = r >> 4, m = r & 15;

    // stage (K = 128, single chunk)
    #pragma unroll
    for (int it = 0; it < 8; ++it) {
        int k8 = (t >> 7) * 8 + it * 16;
        int chunk = k8 >> 5, j = (k8 >> 3) & 3;
        int dstidx = (tile * 4 + chunk) * 64 + j * 16 + m;
        v8s av = {0, 0, 0, 0, 0, 0, 0, 0};
        if (rb + r < n_rows) {
            const float* ap = &A[(size_t)(rb + r) * 128 + k8];
            float4 f0 = *(const float4*)ap;
            float4 f1 = *(const float4*)(ap + 4);
            av[0] = (short)f2bf(f0.x); av[1] = (short)f2bf(f0.y);
            av[2] = (short)f2bf(f0.z); av[3] = (short)f2bf(f0.w);
            av[4] = (short)f2bf(f1.x); av[5] = (short)f2bf(f1.y);
            av[6] = (short)f2bf(f1.z); av[7] = (short)f2bf(f1.w);
        }
        As[dstidx] = av;
        Bs[dstidx] = *(const v8s*)&Bt[(size_t)r * 128 + k8];
    }
    __syncthreads();

    #pragma unroll
    for (int c = 0; c < 4; ++c) {
        v8s a[4], b[4];
        #pragma unroll
        for (int i = 0; i < 4; ++i)
            a[i] = As[((mhalf * 4 + i) * 4 + c) * 64 + l];
        #pragma unroll
        for (int j = 0; j < 4; ++j)
            b[j] = Bs[((nhalf * 4 + j) * 4 + c) * 64 + l];
        #pragma unroll
        for (int i = 0; i < 4; ++i)
            #pragma unroll
            for (int j = 0; j < 4; ++j)
                acc[i][j] = __builtin_amdgcn_mfma_f32_16x16x32_bf16(a[i], b[j], acc[i][j], 0, 0, 0);
    }

    const int coll = l & 15;
    #pragma unroll
    for (int i = 0; i < 4; ++i) {
        int rtile = rb + (mhalf * 4 + i) * 16 + (l >> 4) * 4;
        #pragma unroll
        for (int j = 0; j < 4; ++j) {
            int c = (nhalf * 4 + j) * 16 + coll;
            float bi = bias[c];
            #pragma unroll
            for (int reg = 0; reg < 4; ++reg) {
                int rr = rtile + reg;
                if (rr >= n_rows) continue;
                unsigned short o = f2bf(acc[i][j][reg] + bi);
                if (y == 0)
                    qb[(size_t)rr * 128 + c] = o;
                else
                    kvb[(size_t)rr * 256 + (c >> 1) * 4 + (c & 1) + (y == 2 ? 2 : 0)] = o;
            }
        }
    }
}

// ---- generic bf16 MFMA GEMM (FFN) ------------------------------------------

__global__ __launch_bounds__(256)
void mfma_gemm_kernel(const unsigned short* __restrict__ A,
                      const unsigned short* __restrict__ Bt,
                      const float* __restrict__ bias,
                      unsigned short* __restrict__ Cb,
                      float* __restrict__ Cf,
                      const float* __restrict__ resid,
                      int n_rows, int K, int ncols, int act) {
    __shared__ v8s As[2048];
    __shared__ v8s Bs[2048];

    const int t = threadIdx.x;
    const int l = t & 63;
    const int w = t >> 6;
    const int mhalf = w & 1, nhalf = w >> 1;
    const int rb = blockIdx.x * 128;
    const int cb = blockIdx.y * 128;

    v4f acc[4][4];
    #pragma unroll
    for (int i = 0; i < 4; ++i)
        #pragma unroll
        for (int j = 0; j < 4; ++j)
            acc[i][j] = (v4f){0.f, 0.f, 0.f, 0.f};

    const int r = t & 127;
    const int tile = r >> 4, m = r & 15;

    for (int kc = 0; kc < K; kc += 128) {
        #pragma unroll
        for (int it = 0; it < 8; ++it) {
            int k8 = (t >> 7) * 8 + it * 16;
            int chunk = k8 >> 5, j = (k8 >> 3) & 3;
            int dstidx = (tile * 4 + chunk) * 64 + j * 16 + m;
            v8s av = {0, 0, 0, 0, 0, 0, 0, 0};
            if (rb + r < n_rows)
                av = *(const v8s*)&A[(size_t)(rb + r) * K + kc + k8];
            As[dstidx] = av;
            Bs[dstidx] = *(const v8s*)&Bt[(size_t)(cb + r) * K + kc + k8];
        }
        __syncthreads();

        #pragma unroll
        for (int c = 0; c < 4; ++c) {
            v8s a[4], b[4];
            #pragma unroll
            for (int i = 0; i < 4; ++i)
                a[i] = As[((mhalf * 4 + i) * 4 + c) * 64 + l];
            #pragma unroll
            for (int j = 0; j < 4; ++j)
                b[j] = Bs[((nhalf * 4 + j) * 4 + c) * 64 + l];
            #pragma unroll
            for (int i = 0; i < 4; ++i)
                #pragma unroll
                for (int j = 0; j < 4; ++j)
                    acc[i][j] = __builtin_amdgcn_mfma_f32_16x16x32_bf16(a[i], b[j], acc[i][j], 0, 0, 0);
        }
        __syncthreads();
    }

    const int coll = l & 15;
    #pragma unroll
    for (int i = 0; i < 4; ++i) {
        int rtile = rb + (mhalf * 4 + i) * 16 + (l >> 4) * 4;
        #pragma unroll
        for (int j = 0; j < 4; ++j) {
            int c = cb + (nhalf * 4 + j) * 16 + coll;
            float bi = bias[c];
            #pragma unroll
            for (int reg = 0; reg < 4; ++reg) {
                int rr = rtile + reg;
                if (rr >= n_rows) continue;
                float vv = acc[i][j][reg] + bi;
                if (act) vv = gelu_exact(vv);
                if (Cf) {
                    float o = vv;
                    if (resid) o += resid[(size_t)rr * ncols + c];
                    Cf[(size_t)rr * ncols + c] = o;
                } else {
                    Cb[(size_t)rr * ncols + c] = f2bf(vv);
                }
            }
        }
    }
}

// ---- Attention + residual + LayerNorm, one wave per dst node ---------------
// lane l holds dims {2l,2l+1}; head = l>>3. kvb packed: lane reads uint2
// {k-pair, v-pair} at kvb[s*128 + 2l].

__global__ __launch_bounds__(256)
void attn_ln_kernel(const unsigned short* __restrict__ q,
                    const unsigned int* __restrict__ kvb,
                    const float* __restrict__ x,
                    const int* __restrict__ offs, const int* __restrict__ esrc,
                    const float* __restrict__ ln_g, const float* __restrict__ ln_b,
                    float* __restrict__ hb, unsigned short* __restrict__ hnb, int n) {
    const int wave = threadIdx.x >> 6;
    const int lane = threadIdx.x & 63;
    const int node = blockIdx.x * 4 + wave;
    if (node >= n) return;

    const float2 qv = bf2_to_f2(*(const unsigned int*)&q[(size_t)node * 128 + lane * 2]);
    const int e0 = offs[node], e1 = offs[node + 1];

    float m = -INFINITY, l = 0.f;
    float2 acc = make_float2(0.f, 0.f);

    int j = e0;
    for (; j + 4 <= e1; j += 4) {
        int s0 = esrc[j], s1 = esrc[j + 1], s2 = esrc[j + 2], s3 = esrc[j + 3];
        uint2 kv0 = *(const uint2*)&kvb[(size_t)s0 * 128 + lane * 2];
        uint2 kv1 = *(const uint2*)&kvb[(size_t)s1 * 128 + lane * 2];
        uint2 kv2 = *(const uint2*)&kvb[(size_t)s2 * 128 + lane * 2];
        uint2 kv3 = *(const uint2*)&kvb[(size_t)s3 * 128 + lane * 2];
        float2 k0 = bf2_to_f2(kv0.x), k1 = bf2_to_f2(kv1.x);
        float2 k2 = bf2_to_f2(kv2.x), k3 = bf2_to_f2(kv3.x);
        float p0 = qv.x * k0.x + qv.y * k0.y;
        float p1 = qv.x * k1.x + qv.y * k1.y;
        float p2 = qv.x * k2.x + qv.y * k2.y;
        float p3 = qv.x * k3.x + qv.y * k3.y;
        p0 += __shfl_xor(p0, 1, 64); p1 += __shfl_xor(p1, 1, 64);
        p2 += __shfl_xor(p2, 1, 64); p3 += __shfl_xor(p3, 1, 64);
        p0 += __shfl_xor(p0, 2, 64); p1 += __shfl_xor(p1, 2, 64);
        p2 += __shfl_xor(p2, 2, 64); p3 += __shfl_xor(p3, 2, 64);
        p0 += __shfl_xor(p0, 4, 64); p1 += __shfl_xor(p1, 4, 64);
        p2 += __shfl_xor(p2, 4, 64); p3 += __shfl_xor(p3, 4, 64);
        float sc0 = p0 * 0.25f, sc1 = p1 * 0.25f;
        float sc2 = p2 * 0.25f, sc3 = p3 * 0.25f;
        float mn = fmaxf(fmaxf(m, fmaxf(sc0, sc1)), fmaxf(sc2, sc3));
        float scale = __expf(m - mn);
        float pe0 = __expf(sc0 - mn);
        float pe1 = __expf(sc1 - mn);
        float pe2 = __expf(sc2 - mn);
        float pe3 = __expf(sc3 - mn);
        l = l * scale + ((pe0 + pe1) + (pe2 + pe3));
        float2 v0 = bf2_to_f2(kv0.y), v1 = bf2_to_f2(kv1.y);
        float2 v2 = bf2_to_f2(kv2.y), v3 = bf2_to_f2(kv3.y);
        acc.x = acc.x * scale + ((pe0 * v0.x + pe1 * v1.x) + (pe2 * v2.x + pe3 * v3.x));
        acc.y = acc.y * scale + ((pe0 * v0.y + pe1 * v1.y) + (pe2 * v2.y + pe3 * v3.y));
        m = mn;
    }
    for (; j < e1; ++j) {
        int s0 = esrc[j];
        uint2 kv0 = *(const uint2*)&kvb[(size_t)s0 * 128 + lane * 2];
        float2 k0 = bf2_to_f2(kv0.x);
        float p0 = qv.x * k0.x + qv.y * k0.y;
        p0 += __shfl_xor(p0, 1, 64);
        p0 += __shfl_xor(p0, 2, 64);
        p0 += __shfl_xor(p0, 4, 64);
        float sc0 = p0 * 0.25f;
        float mn = fmaxf(m, sc0);
        float scale = __expf(m - mn);
        float pe0 = __expf(sc0 - mn);
        l = l * scale + pe0;
        float2 v0 = bf2_to_f2(kv0.y);
        acc.x = acc.x * scale + pe0 * v0.x;
        acc.y = acc.y * scale + pe0 * v0.y;
        m = mn;
    }

    float inv = 1.f / (l + 1e-16f);
    float2 xv = *(const float2*)&x[(size_t)node * 128 + lane * 2];
    float2 hv = make_float2(acc.x * inv + xv.x, acc.y * inv + xv.y);
    *(float2*)&hb[(size_t)node * 128 + lane * 2] = hv;

    // fused LayerNorm -> bf16 hn
    float s  = hv.x + hv.y;
    float s2 = hv.x * hv.x + hv.y * hv.y;
    #pragma unroll
    for (int off = 1; off < 64; off <<= 1) {
        s  += __shfl_xor(s, off, 64);
        s2 += __shfl_xor(s2, off, 64);
    }
    float mu  = s * (1.f / 128.f);
    float var = s2 * (1.f / 128.f) - mu * mu;
    float rstd = rsqrtf(var + 1e-5f);
    float2 gv = *(const float2*)&ln_g[lane * 2];
    float2 bv = *(const float2*)&ln_b[lane * 2];
    ushort2 o;
    o.x = f2bf((hv.x - mu) * rstd * gv.x + bv.x);
    o.y = f2bf((hv.y - mu) * rstd * gv.y + bv.y);
    *(ushort2*)&hnb[(size_t)node * 128 + lane * 2] = o;
}

// ---------------------------------------------------------------------------

extern "C" void kernel_launch(void* const* d_in, const int* in_sizes, int n_in,
                              void* d_out, int out_size, void* d_ws, size_t ws_size,
                              hipStream_t stream) {
    const float* x    = (const float*)d_in[0];
    const int*   ei   = (const int*)d_in[1];
    const float* Wq   = (const float*)d_in[2];
    const float* bq   = (const float*)d_in[3];
    const float* Wk   = (const float*)d_in[4];
    const float* bk   = (const float*)d_in[5];
    const float* Wv   = (const float*)d_in[6];
    const float* bv   = (const float*)d_in[7];
    const float* ln_g = (const float*)d_in[8];
    const float* ln_b = (const float*)d_in[9];
    const float* W1   = (const float*)d_in[10];
    const float* b1   = (const float*)d_in[11];
    const float* W2   = (const float*)d_in[12];
    const float* b2   = (const float*)d_in[13];
    float* out = (float*)d_out;

    const int D = 128;
    const int N = in_sizes[0] / D;
    const int E = in_sizes[1] / 2;
    const int* src = ei;
    const int* dst = ei + E;

    const size_t ND = (size_t)N * D;
    unsigned short* qb  = (unsigned short*)d_ws;        // N*128 bf16
    unsigned int*   kvb = (unsigned int*)(qb + ND);     // N*128 uint (packed k/v)
    float*          hb  = (float*)(kvb + ND);           // N*128 fp32
    unsigned short* hnb = (unsigned short*)(hb + ND);   // N*128 bf16
    unsigned short* wcat = hnb + ND;                    // 3*16384
    unsigned short* w1t  = wcat + 49152;                // 32768
    unsigned short* w2t  = w1t + 32768;                 // 32768
    float* bcat = (float*)(w2t + 32768);                // 768 floats
    int* cnt  = (int*)(bcat + 768);
    int* offs = cnt + N;
    int* bsum = offs + N + 1;                           // up to 256
    int* esrc = bsum + 256;                             // E ints
    unsigned short* hid = qb;                           // alias q/kv region: N*256 bf16

    const int nblk = (N + 255) / 256;   // 196

    // CSR build (by dst)
    hipMemsetAsync(cnt, 0, sizeof(int) * N, stream);
    hist_kernel<<<(E + 255) / 256, 256, 0, stream>>>(dst, cnt, E);
    scan_blk_kernel<<<nblk, 256, 0, stream>>>(cnt, offs, bsum, N);
    scan_top_kernel<<<1, 256, 0, stream>>>(bsum, nblk);
    scan_add_kernel<<<nblk, 256, 0, stream>>>(offs, bsum, cnt, N, E);
    scatter_kernel<<<(E + 255) / 256, 256, 0, stream>>>(src, dst, cnt, esrc, E);

    // weights prep (1 dispatch)
    prep_kernel<<<(49152 + 65536 + 768 + 255) / 256, 256, 0, stream>>>(
        Wq, Wk, Wv, W1, W2, bq, bk, bv, b1, b2, wcat, w1t, w2t, bcat);

    // fused QKV projection
    const int rt = (N + 127) / 128;
    qkv_gemm_kernel<<<dim3(rt, 3), 256, 0, stream>>>(x, wcat, bcat, qb, (unsigned short*)kvb, N);

    // attention + residual + LN
    attn_ln_kernel<<<(N + 3) / 4, 256, 0, stream>>>(qb, kvb, x, offs, esrc,
                                                    ln_g, ln_b, hb, hnb, N);

    // FFN
    mfma_gemm_kernel<<<dim3(rt, 2), 256, 0, stream>>>(hnb, w1t, bcat + 384, hid,
                                                      nullptr, nullptr, N, 128, 256, 1);
    mfma_gemm_kernel<<<dim3(rt, 1), 256, 0, stream>>>(hid, w2t, bcat + 640, nullptr,
                                                      out, hb, N, 256, 128, 0);
}